// Round 17
// baseline (63.536 us; speedup 1.0000x reference)
//
#include <hip/hip_runtime.h>

#define FC    75               // K*K*C floats per pixel
#define GPX   32               // pixels per group (2 lanes per pixel)
#define SLABF 2400             // 32 px * 75 floats = 9600 B -> 16 slabs/CU

#define AS1 __attribute__((address_space(1)))
#define AS3 __attribute__((address_space(3)))

typedef float f32x4 __attribute__((ext_vector_type(4), aligned(4)));

// R16 (61.1 us) with ONE change: the img window loads are issued BEFORE the
// filts staging loads. They don't depend on the slab, so their L1/L2 latency
// (~200-400 cyc) hides under the ~900-cyc HBM stage wait instead of being
// exposed at the start of the compute phase. Compute phase is now pure
// ds_read+FMA. Edge groups (2 of 16, wave-uniform) pre-load the same window
// layout via guarded scalars (zero-padded), sharing the static FMA tail.

__global__ __launch_bounds__(64, 4)
void convolve_kernel(const float* __restrict__ img,
                     const float* __restrict__ filts,
                     float* __restrict__ out)
{
    __shared__ float slab[SLABF];

    const int lane = threadIdx.x;          // 0..63
    const int half = lane & 1;
    const int pxi  = lane >> 1;            // 0..31

    // bijective XCD-chunked swizzle (32768 % 8 == 0)
    const int g = ((int)blockIdx.x & 7) * 4096 + ((int)blockIdx.x >> 3);

    const int p  = g * GPX + pxi;           // 32 consecutive pixels, same row
    const int b  = p >> 18;                 // / (512*512)
    const int hw = p & ((1 << 18) - 1);
    const int h  = hw >> 9;
    const int w  = hw & 511;
    const float* imgb = img + (size_t)b * (512u * 512u * 3u);

    // ---- 1. img window -> regs FIRST (independent of the slab) ----
    // layout: window float idx for (row r, dj, c) = dj*3 + c  (0..14)
    f32x4 v[5][4];
    #pragma unroll
    for (int r = 0; r < 5; ++r)
        #pragma unroll
        for (int jj = 0; jj < 4; ++jj)
            v[r][jj] = (f32x4)0.f;

    const int w0 = (g * GPX) & 511;          // wave-uniform: 0,32,...,480
    if (w0 != 0 && w0 != 480) {
        // interior: 20 uniform vector loads (lane pairs share addresses)
        const float* q0 = imgb + (w - 2) * 3;   // (w-2)*3+15 <= 1533 < 1536 ok
        #pragma unroll
        for (int r = 0; r < 5; ++r) {
            const int hh = h + r - 2;
            if ((unsigned)hh < 512u) {           // wave-uniform row guard
                const float* q = q0 + (size_t)hh * 1536;
                v[r][0] = *(const f32x4*)(q);
                v[r][1] = *(const f32x4*)(q + 4);
                v[r][2] = *(const f32x4*)(q + 8);
                v[r][3] = *(const f32x4*)(q + 12);
            }
        }
    } else {
        // edge: guarded scalar fills into the same layout (zero-padded)
        #pragma unroll
        for (int r = 0; r < 5; ++r) {
            const int hh = h + r - 2;
            if ((unsigned)hh < 512u) {
                const float* row = imgb + (size_t)hh * 1536;
                #pragma unroll
                for (int dj = 0; dj < 5; ++dj) {
                    const int ww = w + dj - 2;
                    if ((unsigned)ww < 512u) {
                        #pragma unroll
                        for (int c = 0; c < 3; ++c) {
                            const int idx = dj * 3 + c;     // 0..14, constant
                            v[r][idx >> 2][idx & 3] = row[ww * 3 + c];
                        }
                    }
                }
            }
        }
    }

    // ---- 2. stage this group's 2400 filts floats into LDS (NT) ----
    {
        const f32x4* src4 = (const f32x4*)(filts + (size_t)g * (GPX * FC));
        #pragma unroll
        for (int j = 0; j < 9; ++j) {
            __builtin_amdgcn_global_load_lds(
                (const AS1 void*)(src4 + j * 64 + lane),
                (AS3 void*)(slab + j * 256),
                16, 0, /*aux=NT*/ 2);
        }
        if (lane < 24) {                    // tail: float4 576..599
            __builtin_amdgcn_global_load_lds(
                (const AS1 void*)(src4 + 576 + lane),
                (AS3 void*)(slab + 9 * 256),
                16, 0, /*aux=NT*/ 2);
        }
    }
    asm volatile("s_waitcnt vmcnt(0)" ::: "memory");   // img + slab all landed
    __builtin_amdgcn_sched_barrier(0);      // rule #18: ds_reads stay below wait

    // ---- 3. FMA: static tap selection per half (shared by both paths) ----
    const float* fp = slab + pxi * FC + half * 36;   // half0: dw 0.., half1: dw 36..
    float a0 = 0.f, a1 = 0.f, a2 = 0.f;
    if (!half) {
        #pragma unroll
        for (int T = 0; T < 12; ++T) {
            const int r = T / 5, dj = T % 5;
            const float* fr = fp + T * 3;
            a0 += v[r][(dj*3+0) >> 2][(dj*3+0) & 3] * fr[0];
            a1 += v[r][(dj*3+1) >> 2][(dj*3+1) & 3] * fr[1];
            a2 += v[r][(dj*3+2) >> 2][(dj*3+2) & 3] * fr[2];
        }
    } else {
        #pragma unroll
        for (int T = 12; T < 25; ++T) {
            const int r = T / 5, dj = T % 5;
            const float* fr = fp + (T - 12) * 3;   // base already +36
            a0 += v[r][(dj*3+0) >> 2][(dj*3+0) & 3] * fr[0];
            a1 += v[r][(dj*3+1) >> 2][(dj*3+1) & 3] * fr[1];
            a2 += v[r][(dj*3+2) >> 2][(dj*3+2) & 3] * fr[2];
        }
    }

    // combine lane pair; even lanes store 32 consecutive dwords
    float s = a0 + a1 + a2;
    s += __shfl_xor(s, 1, 64);
    if (!half) out[p] = s;
}

extern "C" void kernel_launch(void* const* d_in, const int* in_sizes, int n_in,
                              void* d_out, int out_size, void* d_ws, size_t ws_size,
                              hipStream_t stream)
{
    const float* img   = (const float*)d_in[0];   // [4,512,512,3]  f32
    const float* filts = (const float*)d_in[1];   // [4,512,512,75] f32
    float* out         = (float*)d_out;           // [4,512,512]    f32

    // 1,048,576 pixels / 32 per block = 32768 blocks of 64 threads
    convolve_kernel<<<32768, 64, 0, stream>>>(img, filts, out);
}

// Round 18
// 59.782 us; speedup vs baseline: 1.0628x; 1.0628x over previous
//
#include <hip/hip_runtime.h>

#define FC    75               // K*K*C floats per pixel
#define GPX   32               // pixels per group (2 lanes per pixel)
#define SLABF 2400             // 32 px * 75 floats = 9600 B -> 16 slabs/CU

#define AS1 __attribute__((address_space(1)))
#define AS3 __attribute__((address_space(3)))

typedef float f32x4 __attribute__((ext_vector_type(4), aligned(4)));

// Issue-order permutation of R16/R17 (the one not yet tried):
//   1. filts staging (critical HBM path) issues FIRST
//   2. img window loads issue SECOND (L1/L2-fast)
//   3. single s_waitcnt vmcnt(0): in-order retirement => wait ~= staging
//      latency; img loads retire underneath it for free.
// R16 exposed img latency after the wait; R17 delayed the stage issue.
// This order gets both benefits. sched_barrier pins stage above img loads.

__global__ __launch_bounds__(64, 4)
void convolve_kernel(const float* __restrict__ img,
                     const float* __restrict__ filts,
                     float* __restrict__ out)
{
    __shared__ float slab[SLABF];

    const int lane = threadIdx.x;          // 0..63
    const int half = lane & 1;
    const int pxi  = lane >> 1;            // 0..31

    // bijective XCD-chunked swizzle (32768 % 8 == 0)
    const int g = ((int)blockIdx.x & 7) * 4096 + ((int)blockIdx.x >> 3);

    // ---- 1. stage this group's 2400 filts floats into LDS (NT), FIRST ----
    {
        const f32x4* src4 = (const f32x4*)(filts + (size_t)g * (GPX * FC));
        #pragma unroll
        for (int j = 0; j < 9; ++j) {
            __builtin_amdgcn_global_load_lds(
                (const AS1 void*)(src4 + j * 64 + lane),
                (AS3 void*)(slab + j * 256),
                16, 0, /*aux=NT*/ 2);
        }
        if (lane < 24) {                    // tail: float4 576..599
            __builtin_amdgcn_global_load_lds(
                (const AS1 void*)(src4 + 576 + lane),
                (AS3 void*)(slab + 9 * 256),
                16, 0, /*aux=NT*/ 2);
        }
    }
    __builtin_amdgcn_sched_barrier(0);      // pin: staging issues before img

    // ---- 2. img window -> regs (latency hides under the stage wait) ----
    const int p  = g * GPX + pxi;           // 32 consecutive pixels, same row
    const int b  = p >> 18;                 // / (512*512)
    const int hw = p & ((1 << 18) - 1);
    const int h  = hw >> 9;
    const int w  = hw & 511;
    const float* imgb = img + (size_t)b * (512u * 512u * 3u);

    // layout: window float idx for (row r, dj, c) = dj*3 + c  (0..14)
    f32x4 v[5][4];
    #pragma unroll
    for (int r = 0; r < 5; ++r)
        #pragma unroll
        for (int jj = 0; jj < 4; ++jj)
            v[r][jj] = (f32x4)0.f;

    const int w0 = (g * GPX) & 511;          // wave-uniform: 0,32,...,480
    if (w0 != 0 && w0 != 480) {
        // interior: 20 uniform vector loads (lane pairs share addresses)
        const float* q0 = imgb + (w - 2) * 3;   // (w-2)*3+15 <= 1533 < 1536 ok
        #pragma unroll
        for (int r = 0; r < 5; ++r) {
            const int hh = h + r - 2;
            if ((unsigned)hh < 512u) {           // wave-uniform row guard
                const float* q = q0 + (size_t)hh * 1536;
                v[r][0] = *(const f32x4*)(q);
                v[r][1] = *(const f32x4*)(q + 4);
                v[r][2] = *(const f32x4*)(q + 8);
                v[r][3] = *(const f32x4*)(q + 12);
            }
        }
    } else {
        // edge: guarded scalar fills into the same layout (zero-padded)
        #pragma unroll
        for (int r = 0; r < 5; ++r) {
            const int hh = h + r - 2;
            if ((unsigned)hh < 512u) {
                const float* row = imgb + (size_t)hh * 1536;
                #pragma unroll
                for (int dj = 0; dj < 5; ++dj) {
                    const int ww = w + dj - 2;
                    if ((unsigned)ww < 512u) {
                        #pragma unroll
                        for (int c = 0; c < 3; ++c) {
                            const int idx = dj * 3 + c;     // 0..14, constant
                            v[r][idx >> 2][idx & 3] = row[ww * 3 + c];
                        }
                    }
                }
            }
        }
    }

    // ---- 3. drain: staging (oldest) + img; wait ~= staging latency ----
    asm volatile("s_waitcnt vmcnt(0)" ::: "memory");
    __builtin_amdgcn_sched_barrier(0);      // rule #18: ds_reads stay below

    // ---- 4. FMA: static tap selection per half ----
    const float* fp = slab + pxi * FC + half * 36;   // half0: dw 0.., half1: dw 36..
    float a0 = 0.f, a1 = 0.f, a2 = 0.f;
    if (!half) {
        #pragma unroll
        for (int T = 0; T < 12; ++T) {
            const int r = T / 5, dj = T % 5;
            const float* fr = fp + T * 3;
            a0 += v[r][(dj*3+0) >> 2][(dj*3+0) & 3] * fr[0];
            a1 += v[r][(dj*3+1) >> 2][(dj*3+1) & 3] * fr[1];
            a2 += v[r][(dj*3+2) >> 2][(dj*3+2) & 3] * fr[2];
        }
    } else {
        #pragma unroll
        for (int T = 12; T < 25; ++T) {
            const int r = T / 5, dj = T % 5;
            const float* fr = fp + (T - 12) * 3;   // base already +36
            a0 += v[r][(dj*3+0) >> 2][(dj*3+0) & 3] * fr[0];
            a1 += v[r][(dj*3+1) >> 2][(dj*3+1) & 3] * fr[1];
            a2 += v[r][(dj*3+2) >> 2][(dj*3+2) & 3] * fr[2];
        }
    }

    // combine lane pair; even lanes store 32 consecutive dwords
    float s = a0 + a1 + a2;
    s += __shfl_xor(s, 1, 64);
    if (!half) out[p] = s;
}

extern "C" void kernel_launch(void* const* d_in, const int* in_sizes, int n_in,
                              void* d_out, int out_size, void* d_ws, size_t ws_size,
                              hipStream_t stream)
{
    const float* img   = (const float*)d_in[0];   // [4,512,512,3]  f32
    const float* filts = (const float*)d_in[1];   // [4,512,512,75] f32
    float* out         = (float*)d_out;           // [4,512,512]    f32

    // 1,048,576 pixels / 32 per block = 32768 blocks of 64 threads
    convolve_kernel<<<32768, 64, 0, stream>>>(img, filts, out);
}